// Round 1
// 1032.125 us; speedup vs baseline: 1.2234x; 1.2234x over previous
//
#include <hip/hip_runtime.h>
#include <hip/hip_bf16.h>

#define NHEADS 3
#define SSH 4
#define NWD 32            // windows per dim
#define PXI 65536         // pixels per image plane
#define SCALE 0.17677669529663687f

// ---------------------------------------------------------------------------
// K1: QKV 1x1 conv for image b (GEMM 288x96 @ 96x65536),
// writes windowed qkv_b [1024][64][288] + V in per-b NCHW [96][PXI]. fp32.
// grid (1024 px-tiles, 3 oc-tiles), block 256
// ---------------------------------------------------------------------------
__global__ __launch_bounds__(256) void k1_qkv(
    const float* __restrict__ x, const float* __restrict__ Wqk,
    const float* __restrict__ bqk, const float* __restrict__ Wv,
    const float* __restrict__ bv, float* __restrict__ qkv_b,
    float* __restrict__ v_b, int b) {
  __shared__ float Wt[96 * 97];   // [c][oc_l] padded
  __shared__ float Xt[96 * 64];   // [c][px]
  const int tid = threadIdx.x;
  const int pt = blockIdx.x, ot = blockIdx.y;
  const int oc0 = ot * 96;
  const int p0 = pt * 64;

  for (int i = tid; i < 96 * 96; i += 256) {
    int c = i % 96, oc_l = i / 96;
    int oc = oc0 + oc_l;
    float w = (oc < 192) ? Wqk[oc * 96 + c] : Wv[(oc - 192) * 96 + c];
    Wt[c * 97 + oc_l] = w;
  }
  for (int i = tid; i < 96 * 64; i += 256) {
    int c = i >> 6, px = i & 63;
    Xt[i] = x[(size_t)(b * 96 + c) * PXI + p0 + px];
  }
  __syncthreads();

  const int tx = tid & 15, ty = tid >> 4;
  float acc[6][4];
#pragma unroll
  for (int r = 0; r < 6; r++)
#pragma unroll
    for (int s = 0; s < 4; s++) acc[r][s] = 0.f;

#pragma unroll 8
  for (int c = 0; c < 96; c++) {
    float xa[4];
#pragma unroll
    for (int s = 0; s < 4; s++) xa[s] = Xt[c * 64 + tx + 16 * s];
#pragma unroll
    for (int r = 0; r < 6; r++) {
      float wv = Wt[c * 97 + ty + 16 * r];
#pragma unroll
      for (int s = 0; s < 4; s++) acc[r][s] += wv * xa[s];
    }
  }

#pragma unroll
  for (int r = 0; r < 6; r++) {
    int oc = oc0 + ty + 16 * r;
    float bb = (oc < 192) ? bqk[oc] : bv[oc - 192];
#pragma unroll
    for (int s = 0; s < 4; s++) {
      int p = p0 + tx + 16 * s;
      float val = acc[r][s] + bb;
      int h = p >> 8, w = p & 255;
      int hp = (h + 252) & 255, wp = (w + 252) & 255;  // rolled coords
      int wh = hp >> 3, ii = hp & 7, ww = wp >> 3, jj = wp & 7;
      int win = wh * NWD + ww;
      int n = ii * 8 + jj;
      qkv_b[(size_t)(win * 64 + n) * 288 + oc] = val;
      if (oc >= 192) v_b[(size_t)(oc - 192) * PXI + p] = val;
    }
  }
}

// ---------------------------------------------------------------------------
// K2: relative-position bias MLP -> bias_ws[head][n][m]  (fp32)
// ---------------------------------------------------------------------------
__global__ __launch_bounds__(256) void k2_bias(
    const float* __restrict__ Wm1, const float* __restrict__ bm1,
    const float* __restrict__ Wm2, const float* __restrict__ bm2,
    float* __restrict__ bias_ws) {
  int pair = blockIdx.x * 256 + threadIdx.x;  // 0..4095
  int n = pair >> 6, m = pair & 63;
  float d0 = (float)((n >> 3) - (m >> 3));
  float d1 = (float)((n & 7) - (m & 7));
  float r0 = (d0 > 0.f ? 1.f : (d0 < 0.f ? -1.f : 0.f)) * log1pf(fabsf(d0));
  float r1 = (d1 > 0.f ? 1.f : (d1 < 0.f ? -1.f : 0.f)) * log1pf(fabsf(d1));
  float a0 = 0.f, a1 = 0.f, a2 = 0.f;
  for (int j = 0; j < 256; j++) {
    float hb = r0 * Wm1[j] + r1 * Wm1[256 + j] + bm1[j];
    hb = fmaxf(hb, 0.f);
    a0 += hb * Wm2[j * 3 + 0];
    a1 += hb * Wm2[j * 3 + 1];
    a2 += hb * Wm2[j * 3 + 2];
  }
  bias_ws[0 * 4096 + pair] = a0 + bm2[0];
  bias_ws[1 * 4096 + pair] = a1 + bm2[1];
  bias_ws[2 * 4096 + pair] = a2 + bm2[2];
}

// ---------------------------------------------------------------------------
// K3: windowed attention, one WAVE per (window, head).
// grid (1024 windows, 3 heads), block 64. No __syncthreads at all:
// wave-internal LDS ordering (in-order DS per wave + lgkmcnt) suffices.
// Register-blocked 8x8 QK / 8x4 PV, shuffle softmax, fp32 throughout.
// LDS plan (floats):  Ps [64][68] @ 0      (PV phase)
//                     Vs [64][36] @ 4352   (PV phase)
//                     Qs [64][36] @ 0      (QK phase, dead before Ps write)
//                     Ks [64][36] @ 2304   (QK phase, tail overlaps Vs head;
//                                           Vs written only after QK reads)
// total 6656 floats = 26624 B -> 6 blocks/CU.
// ---------------------------------------------------------------------------
__global__ __launch_bounds__(64) void k3_attn(
    const float* __restrict__ qkv_b, const float* __restrict__ bias_ws,
    float* __restrict__ o_b) {
  __shared__ __align__(16) float lds[6656];
  float* Ps = lds;              // [64][68]
  float* Vs = lds + 4352;       // [64][36]
  float* Qs = lds;              // [64][36]
  float* Ks = lds + 2304;       // [64][36]

  const int lane = threadIdx.x;
  const int ng = lane & 7;      // QK: row-interleave / PV: row-block
  const int mg = lane >> 3;     // QK: col-interleave / PV: d-block
  const int win = blockIdx.x;
  const int hd = blockIdx.y;
  const int wh = win >> 5, ww = win & 31;

  // ---- bias preload straight into accumulators (L2-hot, hidden by staging)
  float acc[8][8];              // acc[i][j] = S[ng+8i][mg+8j]
  const float* bw = bias_ws + hd * 4096;
#pragma unroll
  for (int i = 0; i < 8; i++)
#pragma unroll
    for (int j = 0; j < 8; j++)
      acc[i][j] = bw[(ng + 8 * i) * 64 + (mg + 8 * j)];

  // ---- stage Q (pre-scaled) and K into LDS (coalesced float4, stride 36)
  const float* qbase = qkv_b + (size_t)win * 64 * 288 + hd * 32;
  const int row8 = lane >> 3, c4 = (lane & 7) * 4;
  {
    float4 qr[8], kr[8];
#pragma unroll
    for (int t = 0; t < 8; t++) {
      const float* src = qbase + (size_t)(t * 8 + row8) * 288 + c4;
      qr[t] = *(const float4*)src;
      kr[t] = *(const float4*)(src + 96);
    }
#pragma unroll
    for (int t = 0; t < 8; t++) {
      int off = (t * 8 + row8) * 36 + c4;
      float4 q = qr[t];
      q.x *= SCALE; q.y *= SCALE; q.z *= SCALE; q.w *= SCALE;
      *(float4*)&Qs[off] = q;
      *(float4*)&Ks[off] = kr[t];
    }
  }

  // ---- shift-mask for edge windows (block-uniform branch; 63/1024 blocks)
  if (wh == 31 || ww == 31) {
    // row r = ng+8i -> ii = i, jj = ng ; col m = mg+8j -> im = j, jm = mg
    int a_n = (ww == 31) ? ((ng < 4) ? 1 : 2) : 0;
    int a_m = (ww == 31) ? ((mg < 4) ? 1 : 2) : 0;
#pragma unroll
    for (int i = 0; i < 8; i++) {
      int rn = ((wh == 31) ? ((i < 4) ? 1 : 2) : 0) * 3 + a_n;
#pragma unroll
      for (int j = 0; j < 8; j++) {
        int rm = ((wh == 31) ? ((j < 4) ? 1 : 2) : 0) * 3 + a_m;
        if (rn != rm) acc[i][j] += -100.f;
      }
    }
  }

  // ---- QK: 8x8 register tile, ds_read_b128 along k
  for (int kq = 0; kq < 8; kq++) {
    float4 qv[8], kv[8];
#pragma unroll
    for (int i = 0; i < 8; i++)
      qv[i] = *(const float4*)&Qs[(ng + 8 * i) * 36 + kq * 4];
#pragma unroll
    for (int j = 0; j < 8; j++)
      kv[j] = *(const float4*)&Ks[(mg + 8 * j) * 36 + kq * 4];
#pragma unroll
    for (int i = 0; i < 8; i++)
#pragma unroll
      for (int j = 0; j < 8; j++)
        acc[i][j] += qv[i].x * kv[j].x + qv[i].y * kv[j].y +
                     qv[i].z * kv[j].z + qv[i].w * kv[j].w;
  }

  // ---- issue V global loads now; latency hides under softmax
  float4 vr[8];
#pragma unroll
  for (int t = 0; t < 8; t++)
    vr[t] = *(const float4*)(qbase + (size_t)(t * 8 + row8) * 288 + 192 + c4);

  // ---- softmax: per-row, tree in regs + 3x shfl_xor over the mg lanes
#pragma unroll
  for (int i = 0; i < 8; i++) {
    float mx = fmaxf(fmaxf(fmaxf(acc[i][0], acc[i][1]),
                           fmaxf(acc[i][2], acc[i][3])),
                     fmaxf(fmaxf(acc[i][4], acc[i][5]),
                           fmaxf(acc[i][6], acc[i][7])));
    mx = fmaxf(mx, __shfl_xor(mx, 8));
    mx = fmaxf(mx, __shfl_xor(mx, 16));
    mx = fmaxf(mx, __shfl_xor(mx, 32));
    float s = 0.f;
#pragma unroll
    for (int j = 0; j < 8; j++) {
      acc[i][j] = __expf(acc[i][j] - mx);
      s += acc[i][j];
    }
    s += __shfl_xor(s, 8);
    s += __shfl_xor(s, 16);
    s += __shfl_xor(s, 32);
    float inv = 1.f / s;
#pragma unroll
    for (int j = 0; j < 8; j++) acc[i][j] *= inv;
  }

  // ---- drain QK reads before overwriting Qs/Ks region with P / Vs with V
  asm volatile("s_waitcnt lgkmcnt(0)" ::: "memory");

  // P transposed into LDS: Pt[m][r], stride 68 (<=2-way banks)
#pragma unroll
  for (int j = 0; j < 8; j++)
#pragma unroll
    for (int i = 0; i < 8; i++)
      Ps[(mg + 8 * j) * 68 + (ng + 8 * i)] = acc[i][j];

  // V into LDS
#pragma unroll
  for (int t = 0; t < 8; t++)
    *(float4*)&Vs[(t * 8 + row8) * 36 + c4] = vr[t];

  // ---- PV: rows r = 8*ng + i, cols d = 4*mg + c
  float o[8][4];
#pragma unroll
  for (int i = 0; i < 8; i++)
#pragma unroll
    for (int c = 0; c < 4; c++) o[i][c] = 0.f;

#pragma unroll 4
  for (int m = 0; m < 64; m++) {
    float4 pa0 = *(const float4*)&Ps[m * 68 + 8 * ng];
    float4 pa1 = *(const float4*)&Ps[m * 68 + 8 * ng + 4];
    float4 vv = *(const float4*)&Vs[m * 36 + 4 * mg];
    float p[8] = {pa0.x, pa0.y, pa0.z, pa0.w, pa1.x, pa1.y, pa1.z, pa1.w};
#pragma unroll
    for (int i = 0; i < 8; i++) {
      o[i][0] += p[i] * vv.x;
      o[i][1] += p[i] * vv.y;
      o[i][2] += p[i] * vv.z;
      o[i][3] += p[i] * vv.w;
    }
  }

  // ---- store: rows r = 8ng+i -> ii = ng, jj = i; float4 along jj
  const int hpix = ((wh << 3) + ng + SSH) & 255;
  const int wb0 = ((ww << 3) + SSH) & 255;        // jj = 0..3
  const int wb1 = ((ww << 3) + 4 + SSH) & 255;    // jj = 4..7
  float* ob = o_b + (size_t)(hd * 32 + 4 * mg) * PXI + (hpix << 8);
#pragma unroll
  for (int c = 0; c < 4; c++) {
    float4 a, b2;
    a.x = o[0][c]; a.y = o[1][c]; a.z = o[2][c]; a.w = o[3][c];
    b2.x = o[4][c]; b2.y = o[5][c]; b2.z = o[6][c]; b2.w = o[7][c];
    *(float4*)&ob[(size_t)c * PXI + wb0] = a;
    *(float4*)&ob[(size_t)c * PXI + wb1] = b2;
  }
}

// ---------------------------------------------------------------------------
// K4: depthwise 5x5 (reflect pad) + bdw + O -> t_b, per image. grid 24576.
// ---------------------------------------------------------------------------
__global__ __launch_bounds__(256) void k4_dw(
    const float* __restrict__ v_b, const float* __restrict__ o_b,
    const float* __restrict__ Wdw, const float* __restrict__ bdw,
    float* __restrict__ t_b) {
  const int blk = blockIdx.x;      // 0..24575
  const int c = blk >> 8;
  const int h = blk & 255;
  const int w = threadIdx.x;
  __shared__ float wd[25];
  __shared__ float bd;
  if (threadIdx.x < 25) wd[threadIdx.x] = Wdw[c * 25 + threadIdx.x];
  if (threadIdx.x == 32) bd = bdw[c];
  __syncthreads();

  const float* vp = v_b + ((size_t)c << 16);
  float acc = bd;
#pragma unroll
  for (int dy = 0; dy < 5; dy++) {
    int hh = h + dy - 2;
    hh = hh < 0 ? -hh : (hh > 255 ? 510 - hh : hh);
    const float* row = vp + (hh << 8);
#pragma unroll
    for (int dx = 0; dx < 5; dx++) {
      int wx = w + dx - 2;
      wx = wx < 0 ? -wx : (wx > 255 ? 510 - wx : wx);
      acc += row[wx] * wd[dy * 5 + dx];
    }
  }
  size_t idx = ((size_t)c << 16) + (h << 8) + w;
  acc += o_b[idx];
  t_b[idx] = acc;
}

// ---------------------------------------------------------------------------
// K5: projection GEMM 96x96 for image b -> d_out (fp32 NCHW). grid 1024.
// ---------------------------------------------------------------------------
__global__ __launch_bounds__(256) void k5_proj(
    const float* __restrict__ t_b, const float* __restrict__ Wp,
    const float* __restrict__ bp, float* __restrict__ out, int b) {
  __shared__ float Wt[96 * 97];
  __shared__ float Xt[96 * 64];
  const int tid = threadIdx.x;
  const int pt = blockIdx.x;
  const int p0 = pt * 64;

  for (int i = tid; i < 96 * 96; i += 256) {
    int c = i % 96, oc_l = i / 96;
    Wt[c * 97 + oc_l] = Wp[oc_l * 96 + c];
  }
  for (int i = tid; i < 96 * 64; i += 256) {
    int c = i >> 6, px = i & 63;
    Xt[i] = t_b[(size_t)c * PXI + p0 + px];
  }
  __syncthreads();

  const int tx = tid & 15, ty = tid >> 4;
  float acc[6][4];
#pragma unroll
  for (int r = 0; r < 6; r++)
#pragma unroll
    for (int s = 0; s < 4; s++) acc[r][s] = 0.f;

#pragma unroll 8
  for (int c = 0; c < 96; c++) {
    float xa[4];
#pragma unroll
    for (int s = 0; s < 4; s++) xa[s] = Xt[c * 64 + tx + 16 * s];
#pragma unroll
    for (int r = 0; r < 6; r++) {
      float wv = Wt[c * 97 + ty + 16 * r];
#pragma unroll
      for (int s = 0; s < 4; s++) acc[r][s] += wv * xa[s];
    }
  }

#pragma unroll
  for (int r = 0; r < 6; r++) {
    int oc = ty + 16 * r;
    float bb = bp[oc];
#pragma unroll
    for (int s = 0; s < 4; s++) {
      int p = p0 + tx + 16 * s;
      out[(size_t)(b * 96 + oc) * PXI + p] = acc[r][s] + bb;
    }
  }
}

// ---------------------------------------------------------------------------
extern "C" void kernel_launch(void* const* d_in, const int* in_sizes, int n_in,
                              void* d_out, int out_size, void* d_ws,
                              size_t ws_size, hipStream_t stream) {
  const float* x   = (const float*)d_in[0];
  const float* Wv  = (const float*)d_in[1];
  const float* bv  = (const float*)d_in[2];
  const float* Wqk = (const float*)d_in[3];
  const float* bqk = (const float*)d_in[4];
  const float* Wm1 = (const float*)d_in[5];
  const float* bm1 = (const float*)d_in[6];
  const float* Wm2 = (const float*)d_in[7];
  const float* bm2 = (const float*)d_in[8];
  const float* Wdw = (const float*)d_in[9];
  const float* bdw = (const float*)d_in[10];
  const float* Wp  = (const float*)d_in[11];
  const float* bp  = (const float*)d_in[12];

  // per-image fp32 workspace (reused across b), total ~120 MiB
  // (R4 proved >= 227.5 MB writable):
  //   [0, 75497472)            qkv_b  fp32 [1024][64][288] (t_b aliases)
  //   [75497472, 100663296)    v_b    fp32 [96][65536]
  //   [100663296, 125829120)   o_b    fp32 [96][65536]
  //   [125829120, 125878272)   bias_ws fp32 [3][64][64]
  char* ws = (char*)d_ws;
  float* qkv_b = (float*)ws;
  float* t_b   = (float*)ws;
  float* v_b   = (float*)(ws + 75497472);
  float* o_b   = (float*)(ws + 100663296);
  float* bias_ws = (float*)(ws + 125829120);

  k2_bias<<<16, 256, 0, stream>>>(Wm1, bm1, Wm2, bm2, bias_ws);
  for (int b = 0; b < 4; b++) {
    k1_qkv<<<dim3(1024, 3), 256, 0, stream>>>(x, Wqk, bqk, Wv, bv, qkv_b, v_b, b);
    k3_attn<<<dim3(1024, 3), 64, 0, stream>>>(qkv_b, bias_ws, o_b);
    k4_dw<<<24576, 256, 0, stream>>>(v_b, o_b, Wdw, bdw, t_b);
    k5_proj<<<1024, 256, 0, stream>>>(t_b, Wp, bp, (float*)d_out, b);
  }
}

// Round 2
// 865.010 us; speedup vs baseline: 1.4598x; 1.1932x over previous
//
#include <hip/hip_runtime.h>
#include <hip/hip_bf16.h>

#define NHEADS 3
#define SSH 4
#define NWD 32            // windows per dim
#define PXI 65536         // pixels per image plane
#define SCALE 0.17677669529663687f

// ---------------------------------------------------------------------------
// K0: one-time weight transposes -> WT[c][oc] (288 wide) and WTp[c][oc] (96).
// Enables wave-uniform scalar (s_load) W reads in k1/k5.
// ---------------------------------------------------------------------------
__global__ __launch_bounds__(256) void k0_wt(
    const float* __restrict__ Wqk, const float* __restrict__ Wv,
    const float* __restrict__ Wp, float* __restrict__ WT,
    float* __restrict__ WTp) {
  int i = blockIdx.x * 256 + threadIdx.x;
  if (i < 288 * 96) {
    int c = i % 96, oc = i / 96;
    float w = (oc < 192) ? Wqk[oc * 96 + c] : Wv[(oc - 192) * 96 + c];
    WT[c * 288 + oc] = w;
  }
  if (i < 96 * 96) {
    int c = i % 96, oc = i / 96;
    WTp[c * 96 + oc] = Wp[oc * 96 + c];
  }
}

// ---------------------------------------------------------------------------
// K1: QKV 1x1 conv for image b (GEMM 288x96 @ 96x65536).
// grid (512 px-tiles, 3 oc-tiles), block 256 (4 waves).
// Each wave owns 24 consecutive oc; W comes via scalar loads from WT
// (wave-uniform address -> s_load, zero LDS/VALU cost). X staged in LDS
// [96][128], one ds_read_b64 per k-step per lane (2 px / lane).
// LDS 48KB -> 3 blocks/CU.
// ---------------------------------------------------------------------------
__global__ __launch_bounds__(256) void k1_qkv(
    const float* __restrict__ x, const float* __restrict__ WT,
    const float* __restrict__ bqk, const float* __restrict__ bv,
    float* __restrict__ qkv_b, float* __restrict__ v_b, int b) {
  __shared__ __align__(16) float Xt[96 * 128];
  const int tid = threadIdx.x;
  const int pt = blockIdx.x, ot = blockIdx.y;
  const int p0 = pt * 128;

  // stage X tile [96 c][128 px], float4 coalesced
  for (int i = tid; i < 96 * 32; i += 256) {
    int c = i >> 5, f = i & 31;
    *(float4*)&Xt[c * 128 + f * 4] =
        *(const float4*)&x[(size_t)(b * 96 + c) * PXI + p0 + f * 4];
  }
  __syncthreads();

  const int lane = tid & 63;
  const int wvu = __builtin_amdgcn_readfirstlane(tid >> 6);  // wave id 0..3
  const int oc0l = wvu * 24;            // oc offset inside 96-tile
  const int oc0 = ot * 96 + oc0l;       // global oc
  const int px = lane * 2;

  float acc[24][2];
#pragma unroll
  for (int r = 0; r < 24; r++) acc[r][0] = acc[r][1] = 0.f;

  const float* wt = WT + oc0;           // wave-uniform base
#pragma unroll 4
  for (int c = 0; c < 96; c++) {
    float2 xa = *(const float2*)&Xt[c * 128 + px];
    const float* wc = wt + c * 288;     // uniform -> s_load
#pragma unroll
    for (int r = 0; r < 24; r++) {
      float w = wc[r];
      acc[r][0] += w * xa.x;
      acc[r][1] += w * xa.y;
    }
  }

  // bias (scalar)
  float bb[24];
#pragma unroll
  for (int r = 0; r < 24; r++) {
    int oc = oc0 + r;
    bb[r] = (oc < 192) ? bqk[oc] : bv[oc - 192];
  }

  // write windowed qkv (float4 along contiguous oc) + V plane (ot==2)
#pragma unroll
  for (int s = 0; s < 2; s++) {
    int p = p0 + px + s;
    int h = p >> 8, w = p & 255;
    int hp = (h + 252) & 255, wp = (w + 252) & 255;  // rolled coords
    int win = (hp >> 3) * NWD + (wp >> 3);
    int n = (hp & 7) * 8 + (wp & 7);
    float* dst = qkv_b + (size_t)(win * 64 + n) * 288 + oc0;
#pragma unroll
    for (int r4 = 0; r4 < 6; r4++) {
      float4 v4;
      v4.x = acc[r4 * 4 + 0][s] + bb[r4 * 4 + 0];
      v4.y = acc[r4 * 4 + 1][s] + bb[r4 * 4 + 1];
      v4.z = acc[r4 * 4 + 2][s] + bb[r4 * 4 + 2];
      v4.w = acc[r4 * 4 + 3][s] + bb[r4 * 4 + 3];
      *(float4*)&dst[r4 * 4] = v4;
    }
    if (ot == 2) {
#pragma unroll
      for (int r = 0; r < 24; r++)
        v_b[(size_t)(oc0l + r) * PXI + p] = acc[r][s] + bb[r];
    }
  }
}

// ---------------------------------------------------------------------------
// K2: relative-position bias MLP -> bias_ws[head][n][m]  (fp32)
// ---------------------------------------------------------------------------
__global__ __launch_bounds__(256) void k2_bias(
    const float* __restrict__ Wm1, const float* __restrict__ bm1,
    const float* __restrict__ Wm2, const float* __restrict__ bm2,
    float* __restrict__ bias_ws) {
  int pair = blockIdx.x * 256 + threadIdx.x;  // 0..4095
  int n = pair >> 6, m = pair & 63;
  float d0 = (float)((n >> 3) - (m >> 3));
  float d1 = (float)((n & 7) - (m & 7));
  float r0 = (d0 > 0.f ? 1.f : (d0 < 0.f ? -1.f : 0.f)) * log1pf(fabsf(d0));
  float r1 = (d1 > 0.f ? 1.f : (d1 < 0.f ? -1.f : 0.f)) * log1pf(fabsf(d1));
  float a0 = 0.f, a1 = 0.f, a2 = 0.f;
  for (int j = 0; j < 256; j++) {
    float hb = r0 * Wm1[j] + r1 * Wm1[256 + j] + bm1[j];
    hb = fmaxf(hb, 0.f);
    a0 += hb * Wm2[j * 3 + 0];
    a1 += hb * Wm2[j * 3 + 1];
    a2 += hb * Wm2[j * 3 + 2];
  }
  bias_ws[0 * 4096 + pair] = a0 + bm2[0];
  bias_ws[1 * 4096 + pair] = a1 + bm2[1];
  bias_ws[2 * 4096 + pair] = a2 + bm2[2];
}

// ---------------------------------------------------------------------------
// K3: windowed attention, one WAVE per (window, head).
// grid (1024 windows, 3 heads), block 64. No __syncthreads at all.
// ---------------------------------------------------------------------------
__global__ __launch_bounds__(64) void k3_attn(
    const float* __restrict__ qkv_b, const float* __restrict__ bias_ws,
    float* __restrict__ o_b) {
  __shared__ __align__(16) float lds[6656];
  float* Ps = lds;              // [64][68]
  float* Vs = lds + 4352;       // [64][36]
  float* Qs = lds;              // [64][36]
  float* Ks = lds + 2304;       // [64][36]

  const int lane = threadIdx.x;
  const int ng = lane & 7;      // QK: row-interleave / PV: row-block
  const int mg = lane >> 3;     // QK: col-interleave / PV: d-block
  const int win = blockIdx.x;
  const int hd = blockIdx.y;
  const int wh = win >> 5, ww = win & 31;

  // ---- bias preload straight into accumulators
  float acc[8][8];              // acc[i][j] = S[ng+8i][mg+8j]
  const float* bw = bias_ws + hd * 4096;
#pragma unroll
  for (int i = 0; i < 8; i++)
#pragma unroll
    for (int j = 0; j < 8; j++)
      acc[i][j] = bw[(ng + 8 * i) * 64 + (mg + 8 * j)];

  // ---- stage Q (pre-scaled) and K into LDS (coalesced float4, stride 36)
  const float* qbase = qkv_b + (size_t)win * 64 * 288 + hd * 32;
  const int row8 = lane >> 3, c4 = (lane & 7) * 4;
  {
    float4 qr[8], kr[8];
#pragma unroll
    for (int t = 0; t < 8; t++) {
      const float* src = qbase + (size_t)(t * 8 + row8) * 288 + c4;
      qr[t] = *(const float4*)src;
      kr[t] = *(const float4*)(src + 96);
    }
#pragma unroll
    for (int t = 0; t < 8; t++) {
      int off = (t * 8 + row8) * 36 + c4;
      float4 q = qr[t];
      q.x *= SCALE; q.y *= SCALE; q.z *= SCALE; q.w *= SCALE;
      *(float4*)&Qs[off] = q;
      *(float4*)&Ks[off] = kr[t];
    }
  }

  // ---- shift-mask for edge windows (block-uniform branch)
  if (wh == 31 || ww == 31) {
    int a_n = (ww == 31) ? ((ng < 4) ? 1 : 2) : 0;
    int a_m = (ww == 31) ? ((mg < 4) ? 1 : 2) : 0;
#pragma unroll
    for (int i = 0; i < 8; i++) {
      int rn = ((wh == 31) ? ((i < 4) ? 1 : 2) : 0) * 3 + a_n;
#pragma unroll
      for (int j = 0; j < 8; j++) {
        int rm = ((wh == 31) ? ((j < 4) ? 1 : 2) : 0) * 3 + a_m;
        if (rn != rm) acc[i][j] += -100.f;
      }
    }
  }

  // ---- QK: 8x8 register tile, ds_read_b128 along k
  for (int kq = 0; kq < 8; kq++) {
    float4 qv[8], kv[8];
#pragma unroll
    for (int i = 0; i < 8; i++)
      qv[i] = *(const float4*)&Qs[(ng + 8 * i) * 36 + kq * 4];
#pragma unroll
    for (int j = 0; j < 8; j++)
      kv[j] = *(const float4*)&Ks[(mg + 8 * j) * 36 + kq * 4];
#pragma unroll
    for (int i = 0; i < 8; i++)
#pragma unroll
      for (int j = 0; j < 8; j++)
        acc[i][j] += qv[i].x * kv[j].x + qv[i].y * kv[j].y +
                     qv[i].z * kv[j].z + qv[i].w * kv[j].w;
  }

  // ---- issue V global loads now; latency hides under softmax
  float4 vr[8];
#pragma unroll
  for (int t = 0; t < 8; t++)
    vr[t] = *(const float4*)(qbase + (size_t)(t * 8 + row8) * 288 + 192 + c4);

  // ---- softmax: per-row, tree in regs + 3x shfl_xor over the mg lanes
#pragma unroll
  for (int i = 0; i < 8; i++) {
    float mx = fmaxf(fmaxf(fmaxf(acc[i][0], acc[i][1]),
                           fmaxf(acc[i][2], acc[i][3])),
                     fmaxf(fmaxf(acc[i][4], acc[i][5]),
                           fmaxf(acc[i][6], acc[i][7])));
    mx = fmaxf(mx, __shfl_xor(mx, 8));
    mx = fmaxf(mx, __shfl_xor(mx, 16));
    mx = fmaxf(mx, __shfl_xor(mx, 32));
    float s = 0.f;
#pragma unroll
    for (int j = 0; j < 8; j++) {
      acc[i][j] = __expf(acc[i][j] - mx);
      s += acc[i][j];
    }
    s += __shfl_xor(s, 8);
    s += __shfl_xor(s, 16);
    s += __shfl_xor(s, 32);
    float inv = 1.f / s;
#pragma unroll
    for (int j = 0; j < 8; j++) acc[i][j] *= inv;
  }

  // ---- drain QK reads before overwriting Qs/Ks region with P / Vs with V
  asm volatile("s_waitcnt lgkmcnt(0)" ::: "memory");

  // P transposed into LDS: Pt[m][r], stride 68
#pragma unroll
  for (int j = 0; j < 8; j++)
#pragma unroll
    for (int i = 0; i < 8; i++)
      Ps[(mg + 8 * j) * 68 + (ng + 8 * i)] = acc[i][j];

  // V into LDS
#pragma unroll
  for (int t = 0; t < 8; t++)
    *(float4*)&Vs[(t * 8 + row8) * 36 + c4] = vr[t];

  // ---- PV: rows r = 8*ng + i, cols d = 4*mg + c
  float o[8][4];
#pragma unroll
  for (int i = 0; i < 8; i++)
#pragma unroll
    for (int c = 0; c < 4; c++) o[i][c] = 0.f;

#pragma unroll 4
  for (int m = 0; m < 64; m++) {
    float4 pa0 = *(const float4*)&Ps[m * 68 + 8 * ng];
    float4 pa1 = *(const float4*)&Ps[m * 68 + 8 * ng + 4];
    float4 vv = *(const float4*)&Vs[m * 36 + 4 * mg];
    float p[8] = {pa0.x, pa0.y, pa0.z, pa0.w, pa1.x, pa1.y, pa1.z, pa1.w};
#pragma unroll
    for (int i = 0; i < 8; i++) {
      o[i][0] += p[i] * vv.x;
      o[i][1] += p[i] * vv.y;
      o[i][2] += p[i] * vv.z;
      o[i][3] += p[i] * vv.w;
    }
  }

  // ---- store: rows r = 8ng+i -> ii = ng, jj = i; float4 along jj
  const int hpix = ((wh << 3) + ng + SSH) & 255;
  const int wb0 = ((ww << 3) + SSH) & 255;        // jj = 0..3
  const int wb1 = ((ww << 3) + 4 + SSH) & 255;    // jj = 4..7
  float* ob = o_b + (size_t)(hd * 32 + 4 * mg) * PXI + (hpix << 8);
#pragma unroll
  for (int c = 0; c < 4; c++) {
    float4 a, b2;
    a.x = o[0][c]; a.y = o[1][c]; a.z = o[2][c]; a.w = o[3][c];
    b2.x = o[4][c]; b2.y = o[5][c]; b2.z = o[6][c]; b2.w = o[7][c];
    *(float4*)&ob[(size_t)c * PXI + wb0] = a;
    *(float4*)&ob[(size_t)c * PXI + wb1] = b2;
  }
}

// ---------------------------------------------------------------------------
// K4: depthwise 5x5 (reflect pad) + bdw + O -> t_b, per image. grid 24576.
// ---------------------------------------------------------------------------
__global__ __launch_bounds__(256) void k4_dw(
    const float* __restrict__ v_b, const float* __restrict__ o_b,
    const float* __restrict__ Wdw, const float* __restrict__ bdw,
    float* __restrict__ t_b) {
  const int blk = blockIdx.x;      // 0..24575
  const int c = blk >> 8;
  const int h = blk & 255;
  const int w = threadIdx.x;
  __shared__ float wd[25];
  __shared__ float bd;
  if (threadIdx.x < 25) wd[threadIdx.x] = Wdw[c * 25 + threadIdx.x];
  if (threadIdx.x == 32) bd = bdw[c];
  __syncthreads();

  const float* vp = v_b + ((size_t)c << 16);
  float acc = bd;
#pragma unroll
  for (int dy = 0; dy < 5; dy++) {
    int hh = h + dy - 2;
    hh = hh < 0 ? -hh : (hh > 255 ? 510 - hh : hh);
    const float* row = vp + (hh << 8);
#pragma unroll
    for (int dx = 0; dx < 5; dx++) {
      int wx = w + dx - 2;
      wx = wx < 0 ? -wx : (wx > 255 ? 510 - wx : wx);
      acc += row[wx] * wd[dy * 5 + dx];
    }
  }
  size_t idx = ((size_t)c << 16) + (h << 8) + w;
  acc += o_b[idx];
  t_b[idx] = acc;
}

// ---------------------------------------------------------------------------
// K5: projection GEMM 96x96 for image b -> d_out (fp32 NCHW).
// Same scalar-W scheme as k1. grid 512, block 256 (4 waves x 24 oc).
// ---------------------------------------------------------------------------
__global__ __launch_bounds__(256) void k5_proj(
    const float* __restrict__ t_b, const float* __restrict__ WTp,
    const float* __restrict__ bp, float* __restrict__ out, int b) {
  __shared__ __align__(16) float Xt[96 * 128];
  const int tid = threadIdx.x;
  const int pt = blockIdx.x;
  const int p0 = pt * 128;

  for (int i = tid; i < 96 * 32; i += 256) {
    int c = i >> 5, f = i & 31;
    *(float4*)&Xt[c * 128 + f * 4] =
        *(const float4*)&t_b[(size_t)c * PXI + p0 + f * 4];
  }
  __syncthreads();

  const int lane = tid & 63;
  const int wvu = __builtin_amdgcn_readfirstlane(tid >> 6);
  const int oc0 = wvu * 24;
  const int px = lane * 2;

  float acc[24][2];
#pragma unroll
  for (int r = 0; r < 24; r++) acc[r][0] = acc[r][1] = 0.f;

  const float* wt = WTp + oc0;
#pragma unroll 4
  for (int c = 0; c < 96; c++) {
    float2 xa = *(const float2*)&Xt[c * 128 + px];
    const float* wc = wt + c * 96;      // uniform -> s_load
#pragma unroll
    for (int r = 0; r < 24; r++) {
      float w = wc[r];
      acc[r][0] += w * xa.x;
      acc[r][1] += w * xa.y;
    }
  }

#pragma unroll
  for (int r = 0; r < 24; r++) {
    int oc = oc0 + r;
    float bb = bp[oc];
    float2 v2;
    v2.x = acc[r][0] + bb;
    v2.y = acc[r][1] + bb;
    *(float2*)&out[(size_t)(b * 96 + oc) * PXI + p0 + px] = v2;
  }
}

// ---------------------------------------------------------------------------
extern "C" void kernel_launch(void* const* d_in, const int* in_sizes, int n_in,
                              void* d_out, int out_size, void* d_ws,
                              size_t ws_size, hipStream_t stream) {
  const float* x   = (const float*)d_in[0];
  const float* Wv  = (const float*)d_in[1];
  const float* bv  = (const float*)d_in[2];
  const float* Wqk = (const float*)d_in[3];
  const float* bqk = (const float*)d_in[4];
  const float* Wm1 = (const float*)d_in[5];
  const float* bm1 = (const float*)d_in[6];
  const float* Wm2 = (const float*)d_in[7];
  const float* bm2 = (const float*)d_in[8];
  const float* Wdw = (const float*)d_in[9];
  const float* bdw = (const float*)d_in[10];
  const float* Wp  = (const float*)d_in[11];
  const float* bp  = (const float*)d_in[12];

  // per-image fp32 workspace (reused across b):
  //   [0, 75497472)            qkv_b  fp32 [1024][64][288] (t_b aliases)
  //   [75497472, 100663296)    v_b    fp32 [96][65536]
  //   [100663296, 125829120)   o_b    fp32 [96][65536]
  //   [125829120, 125878272)   bias_ws fp32 [3][64][64]
  //   [125878272, 125988864)   WT  fp32 [96][288]
  //   [125988864, 126025728)   WTp fp32 [96][96]
  char* ws = (char*)d_ws;
  float* qkv_b = (float*)ws;
  float* t_b   = (float*)ws;
  float* v_b   = (float*)(ws + 75497472);
  float* o_b   = (float*)(ws + 100663296);
  float* bias_ws = (float*)(ws + 125829120);
  float* WT    = (float*)(ws + 125878272);
  float* WTp   = (float*)(ws + 125988864);

  k0_wt<<<108, 256, 0, stream>>>(Wqk, Wv, Wp, WT, WTp);
  k2_bias<<<16, 256, 0, stream>>>(Wm1, bm1, Wm2, bm2, bias_ws);
  for (int b = 0; b < 4; b++) {
    k1_qkv<<<dim3(512, 3), 256, 0, stream>>>(x, WT, bqk, bv, qkv_b, v_b, b);
    k3_attn<<<dim3(1024, 3), 64, 0, stream>>>(qkv_b, bias_ws, o_b);
    k4_dw<<<24576, 256, 0, stream>>>(v_b, o_b, Wdw, bdw, t_b);
    k5_proj<<<512, 256, 0, stream>>>(t_b, WTp, bp, (float*)d_out, b);
  }
}

// Round 3
// 829.631 us; speedup vs baseline: 1.5220x; 1.0426x over previous
//
#include <hip/hip_runtime.h>
#include <hip/hip_bf16.h>

#define NHEADS 3
#define SSH 4
#define NWD 32            // windows per dim
#define PXI 65536         // pixels per image plane
#define SCALE 0.17677669529663687f

// ---------------------------------------------------------------------------
// K0: one-time weight transposes -> WT[c][oc] (288 wide) and WTp[c][oc] (96).
// Enables wave-uniform scalar (s_load) W reads in k1/k5.
// ---------------------------------------------------------------------------
__global__ __launch_bounds__(256) void k0_wt(
    const float* __restrict__ Wqk, const float* __restrict__ Wv,
    const float* __restrict__ Wp, float* __restrict__ WT,
    float* __restrict__ WTp) {
  int i = blockIdx.x * 256 + threadIdx.x;
  if (i < 288 * 96) {
    int c = i % 96, oc = i / 96;
    float w = (oc < 192) ? Wqk[oc * 96 + c] : Wv[(oc - 192) * 96 + c];
    WT[c * 288 + oc] = w;
  }
  if (i < 96 * 96) {
    int c = i % 96, oc = i / 96;
    WTp[c * 96 + oc] = Wp[oc * 96 + c];
  }
}

// ---------------------------------------------------------------------------
// K1: QKV 1x1 conv for image b (GEMM 288x96 @ 96x65536).
// grid (1024 px-tiles, 3 oc-tiles), block 256 (4 waves).
// 64-px tiles: LDS 24KB -> 6 blocks/CU = 24 waves/CU (was 12) for latency
// hiding. Each wave owns 24 consecutive oc; W via wave-uniform s_load from
// WT; X from LDS, 1 ds_read_b32 + 24 scalar-FMA per k-step.
// ---------------------------------------------------------------------------
__global__ __launch_bounds__(256) void k1_qkv(
    const float* __restrict__ x, const float* __restrict__ WT,
    const float* __restrict__ bqk, const float* __restrict__ bv,
    float* __restrict__ qkv_b, float* __restrict__ v_b, int b) {
  __shared__ __align__(16) float Xt[96 * 64];
  const int tid = threadIdx.x;
  const int pt = blockIdx.x, ot = blockIdx.y;
  const int p0 = pt * 64;

  // stage X tile [96 c][64 px], float4 coalesced
  for (int i = tid; i < 96 * 16; i += 256) {
    int c = i >> 4, f = i & 15;
    *(float4*)&Xt[c * 64 + f * 4] =
        *(const float4*)&x[(size_t)(b * 96 + c) * PXI + p0 + f * 4];
  }
  __syncthreads();

  const int lane = tid & 63;
  const int wvu = __builtin_amdgcn_readfirstlane(tid >> 6);  // wave id 0..3
  const int oc0l = wvu * 24;            // oc offset inside 96-tile
  const int oc0 = ot * 96 + oc0l;       // global oc

  float acc[24];
#pragma unroll
  for (int r = 0; r < 24; r++) acc[r] = 0.f;

  const float* wt = WT + oc0;           // wave-uniform base
#pragma unroll 4
  for (int c = 0; c < 96; c++) {
    float xa = Xt[c * 64 + lane];
    const float* wc = wt + c * 288;     // uniform -> s_load
#pragma unroll
    for (int r = 0; r < 24; r++) acc[r] += wc[r] * xa;
  }

  // bias (scalar)
  float bb[24];
#pragma unroll
  for (int r = 0; r < 24; r++) {
    int oc = oc0 + r;
    bb[r] = (oc < 192) ? bqk[oc] : bv[oc - 192];
  }

  // write windowed qkv (float4 along contiguous oc) + V plane (ot==2)
  {
    int p = p0 + lane;
    int h = p >> 8, w = p & 255;
    int hp = (h + 252) & 255, wp = (w + 252) & 255;  // rolled coords
    int win = (hp >> 3) * NWD + (wp >> 3);
    int n = (hp & 7) * 8 + (wp & 7);
    float* dst = qkv_b + (size_t)(win * 64 + n) * 288 + oc0;
#pragma unroll
    for (int r4 = 0; r4 < 6; r4++) {
      float4 v4;
      v4.x = acc[r4 * 4 + 0] + bb[r4 * 4 + 0];
      v4.y = acc[r4 * 4 + 1] + bb[r4 * 4 + 1];
      v4.z = acc[r4 * 4 + 2] + bb[r4 * 4 + 2];
      v4.w = acc[r4 * 4 + 3] + bb[r4 * 4 + 3];
      *(float4*)&dst[r4 * 4] = v4;
    }
    if (ot == 2) {
#pragma unroll
      for (int r = 0; r < 24; r++)
        v_b[(size_t)(oc0l + r) * PXI + p] = acc[r] + bb[r];
    }
  }
}

// ---------------------------------------------------------------------------
// K2: relative-position bias MLP -> bias_ws[head][n][m]  (fp32)
// ---------------------------------------------------------------------------
__global__ __launch_bounds__(256) void k2_bias(
    const float* __restrict__ Wm1, const float* __restrict__ bm1,
    const float* __restrict__ Wm2, const float* __restrict__ bm2,
    float* __restrict__ bias_ws) {
  int pair = blockIdx.x * 256 + threadIdx.x;  // 0..4095
  int n = pair >> 6, m = pair & 63;
  float d0 = (float)((n >> 3) - (m >> 3));
  float d1 = (float)((n & 7) - (m & 7));
  float r0 = (d0 > 0.f ? 1.f : (d0 < 0.f ? -1.f : 0.f)) * log1pf(fabsf(d0));
  float r1 = (d1 > 0.f ? 1.f : (d1 < 0.f ? -1.f : 0.f)) * log1pf(fabsf(d1));
  float a0 = 0.f, a1 = 0.f, a2 = 0.f;
  for (int j = 0; j < 256; j++) {
    float hb = r0 * Wm1[j] + r1 * Wm1[256 + j] + bm1[j];
    hb = fmaxf(hb, 0.f);
    a0 += hb * Wm2[j * 3 + 0];
    a1 += hb * Wm2[j * 3 + 1];
    a2 += hb * Wm2[j * 3 + 2];
  }
  bias_ws[0 * 4096 + pair] = a0 + bm2[0];
  bias_ws[1 * 4096 + pair] = a1 + bm2[1];
  bias_ws[2 * 4096 + pair] = a2 + bm2[2];
}

// ---------------------------------------------------------------------------
// K3: windowed attention, one WAVE per (window, head).
// grid (1024 windows, 3 heads), block 64. No __syncthreads at all.
// ---------------------------------------------------------------------------
__global__ __launch_bounds__(64) void k3_attn(
    const float* __restrict__ qkv_b, const float* __restrict__ bias_ws,
    float* __restrict__ o_b) {
  __shared__ __align__(16) float lds[6656];
  float* Ps = lds;              // [64][68]
  float* Vs = lds + 4352;       // [64][36]
  float* Qs = lds;              // [64][36]
  float* Ks = lds + 2304;       // [64][36]

  const int lane = threadIdx.x;
  const int ng = lane & 7;      // QK: row-interleave / PV: row-block
  const int mg = lane >> 3;     // QK: col-interleave / PV: d-block
  const int win = blockIdx.x;
  const int hd = blockIdx.y;
  const int wh = win >> 5, ww = win & 31;

  // ---- bias preload straight into accumulators
  float acc[8][8];              // acc[i][j] = S[ng+8i][mg+8j]
  const float* bw = bias_ws + hd * 4096;
#pragma unroll
  for (int i = 0; i < 8; i++)
#pragma unroll
    for (int j = 0; j < 8; j++)
      acc[i][j] = bw[(ng + 8 * i) * 64 + (mg + 8 * j)];

  // ---- stage Q (pre-scaled) and K into LDS (coalesced float4, stride 36)
  const float* qbase = qkv_b + (size_t)win * 64 * 288 + hd * 32;
  const int row8 = lane >> 3, c4 = (lane & 7) * 4;
  {
    float4 qr[8], kr[8];
#pragma unroll
    for (int t = 0; t < 8; t++) {
      const float* src = qbase + (size_t)(t * 8 + row8) * 288 + c4;
      qr[t] = *(const float4*)src;
      kr[t] = *(const float4*)(src + 96);
    }
#pragma unroll
    for (int t = 0; t < 8; t++) {
      int off = (t * 8 + row8) * 36 + c4;
      float4 q = qr[t];
      q.x *= SCALE; q.y *= SCALE; q.z *= SCALE; q.w *= SCALE;
      *(float4*)&Qs[off] = q;
      *(float4*)&Ks[off] = kr[t];
    }
  }

  // ---- shift-mask for edge windows (block-uniform branch)
  if (wh == 31 || ww == 31) {
    int a_n = (ww == 31) ? ((ng < 4) ? 1 : 2) : 0;
    int a_m = (ww == 31) ? ((mg < 4) ? 1 : 2) : 0;
#pragma unroll
    for (int i = 0; i < 8; i++) {
      int rn = ((wh == 31) ? ((i < 4) ? 1 : 2) : 0) * 3 + a_n;
#pragma unroll
      for (int j = 0; j < 8; j++) {
        int rm = ((wh == 31) ? ((j < 4) ? 1 : 2) : 0) * 3 + a_m;
        if (rn != rm) acc[i][j] += -100.f;
      }
    }
  }

  // ---- QK: 8x8 register tile, ds_read_b128 along k
  for (int kq = 0; kq < 8; kq++) {
    float4 qv[8], kv[8];
#pragma unroll
    for (int i = 0; i < 8; i++)
      qv[i] = *(const float4*)&Qs[(ng + 8 * i) * 36 + kq * 4];
#pragma unroll
    for (int j = 0; j < 8; j++)
      kv[j] = *(const float4*)&Ks[(mg + 8 * j) * 36 + kq * 4];
#pragma unroll
    for (int i = 0; i < 8; i++)
#pragma unroll
      for (int j = 0; j < 8; j++)
        acc[i][j] += qv[i].x * kv[j].x + qv[i].y * kv[j].y +
                     qv[i].z * kv[j].z + qv[i].w * kv[j].w;
  }

  // ---- issue V global loads now; latency hides under softmax
  float4 vr[8];
#pragma unroll
  for (int t = 0; t < 8; t++)
    vr[t] = *(const float4*)(qbase + (size_t)(t * 8 + row8) * 288 + 192 + c4);

  // ---- softmax: per-row, tree in regs + 3x shfl_xor over the mg lanes
#pragma unroll
  for (int i = 0; i < 8; i++) {
    float mx = fmaxf(fmaxf(fmaxf(acc[i][0], acc[i][1]),
                           fmaxf(acc[i][2], acc[i][3])),
                     fmaxf(fmaxf(acc[i][4], acc[i][5]),
                           fmaxf(acc[i][6], acc[i][7])));
    mx = fmaxf(mx, __shfl_xor(mx, 8));
    mx = fmaxf(mx, __shfl_xor(mx, 16));
    mx = fmaxf(mx, __shfl_xor(mx, 32));
    float s = 0.f;
#pragma unroll
    for (int j = 0; j < 8; j++) {
      acc[i][j] = __expf(acc[i][j] - mx);
      s += acc[i][j];
    }
    s += __shfl_xor(s, 8);
    s += __shfl_xor(s, 16);
    s += __shfl_xor(s, 32);
    float inv = 1.f / s;
#pragma unroll
    for (int j = 0; j < 8; j++) acc[i][j] *= inv;
  }

  // ---- drain QK reads before overwriting Qs/Ks region with P / Vs with V
  asm volatile("s_waitcnt lgkmcnt(0)" ::: "memory");

  // P transposed into LDS: Pt[m][r], stride 68
#pragma unroll
  for (int j = 0; j < 8; j++)
#pragma unroll
    for (int i = 0; i < 8; i++)
      Ps[(mg + 8 * j) * 68 + (ng + 8 * i)] = acc[i][j];

  // V into LDS
#pragma unroll
  for (int t = 0; t < 8; t++)
    *(float4*)&Vs[(t * 8 + row8) * 36 + c4] = vr[t];

  // ---- PV: rows r = 8*ng + i, cols d = 4*mg + c
  float o[8][4];
#pragma unroll
  for (int i = 0; i < 8; i++)
#pragma unroll
    for (int c = 0; c < 4; c++) o[i][c] = 0.f;

#pragma unroll 4
  for (int m = 0; m < 64; m++) {
    float4 pa0 = *(const float4*)&Ps[m * 68 + 8 * ng];
    float4 pa1 = *(const float4*)&Ps[m * 68 + 8 * ng + 4];
    float4 vv = *(const float4*)&Vs[m * 36 + 4 * mg];
    float p[8] = {pa0.x, pa0.y, pa0.z, pa0.w, pa1.x, pa1.y, pa1.z, pa1.w};
#pragma unroll
    for (int i = 0; i < 8; i++) {
      o[i][0] += p[i] * vv.x;
      o[i][1] += p[i] * vv.y;
      o[i][2] += p[i] * vv.z;
      o[i][3] += p[i] * vv.w;
    }
  }

  // ---- store: rows r = 8ng+i -> ii = ng, jj = i; float4 along jj
  const int hpix = ((wh << 3) + ng + SSH) & 255;
  const int wb0 = ((ww << 3) + SSH) & 255;        // jj = 0..3
  const int wb1 = ((ww << 3) + 4 + SSH) & 255;    // jj = 4..7
  float* ob = o_b + (size_t)(hd * 32 + 4 * mg) * PXI + (hpix << 8);
#pragma unroll
  for (int c = 0; c < 4; c++) {
    float4 a, b2;
    a.x = o[0][c]; a.y = o[1][c]; a.z = o[2][c]; a.w = o[3][c];
    b2.x = o[4][c]; b2.y = o[5][c]; b2.z = o[6][c]; b2.w = o[7][c];
    *(float4*)&ob[(size_t)c * PXI + wb0] = a;
    *(float4*)&ob[(size_t)c * PXI + wb1] = b2;
  }
}

// ---------------------------------------------------------------------------
// K4: depthwise 5x5 (reflect pad) + bdw + O -> t_b, per image. grid 24576.
// ---------------------------------------------------------------------------
__global__ __launch_bounds__(256) void k4_dw(
    const float* __restrict__ v_b, const float* __restrict__ o_b,
    const float* __restrict__ Wdw, const float* __restrict__ bdw,
    float* __restrict__ t_b) {
  const int blk = blockIdx.x;      // 0..24575
  const int c = blk >> 8;
  const int h = blk & 255;
  const int w = threadIdx.x;
  __shared__ float wd[25];
  __shared__ float bd;
  if (threadIdx.x < 25) wd[threadIdx.x] = Wdw[c * 25 + threadIdx.x];
  if (threadIdx.x == 32) bd = bdw[c];
  __syncthreads();

  const float* vp = v_b + ((size_t)c << 16);
  float acc = bd;
#pragma unroll
  for (int dy = 0; dy < 5; dy++) {
    int hh = h + dy - 2;
    hh = hh < 0 ? -hh : (hh > 255 ? 510 - hh : hh);
    const float* row = vp + (hh << 8);
#pragma unroll
    for (int dx = 0; dx < 5; dx++) {
      int wx = w + dx - 2;
      wx = wx < 0 ? -wx : (wx > 255 ? 510 - wx : wx);
      acc += row[wx] * wd[dy * 5 + dx];
    }
  }
  size_t idx = ((size_t)c << 16) + (h << 8) + w;
  acc += o_b[idx];
  t_b[idx] = acc;
}

// ---------------------------------------------------------------------------
// K5: projection GEMM 96x96 for image b -> d_out (fp32 NCHW).
// Same scheme as k1: 64-px tiles, 24KB LDS, 6 blocks/CU. grid 1024.
// ---------------------------------------------------------------------------
__global__ __launch_bounds__(256) void k5_proj(
    const float* __restrict__ t_b, const float* __restrict__ WTp,
    const float* __restrict__ bp, float* __restrict__ out, int b) {
  __shared__ __align__(16) float Xt[96 * 64];
  const int tid = threadIdx.x;
  const int pt = blockIdx.x;
  const int p0 = pt * 64;

  for (int i = tid; i < 96 * 16; i += 256) {
    int c = i >> 4, f = i & 15;
    *(float4*)&Xt[c * 64 + f * 4] =
        *(const float4*)&t_b[(size_t)c * PXI + p0 + f * 4];
  }
  __syncthreads();

  const int lane = tid & 63;
  const int wvu = __builtin_amdgcn_readfirstlane(tid >> 6);
  const int oc0 = wvu * 24;

  float acc[24];
#pragma unroll
  for (int r = 0; r < 24; r++) acc[r] = 0.f;

  const float* wt = WTp + oc0;
#pragma unroll 4
  for (int c = 0; c < 96; c++) {
    float xa = Xt[c * 64 + lane];
    const float* wc = wt + c * 96;      // uniform -> s_load
#pragma unroll
    for (int r = 0; r < 24; r++) acc[r] += wc[r] * xa;
  }

  int p = p0 + lane;
#pragma unroll
  for (int r = 0; r < 24; r++) {
    int oc = oc0 + r;
    out[(size_t)(b * 96 + oc) * PXI + p] = acc[r] + bp[oc];
  }
}

// ---------------------------------------------------------------------------
extern "C" void kernel_launch(void* const* d_in, const int* in_sizes, int n_in,
                              void* d_out, int out_size, void* d_ws,
                              size_t ws_size, hipStream_t stream) {
  const float* x   = (const float*)d_in[0];
  const float* Wv  = (const float*)d_in[1];
  const float* bv  = (const float*)d_in[2];
  const float* Wqk = (const float*)d_in[3];
  const float* bqk = (const float*)d_in[4];
  const float* Wm1 = (const float*)d_in[5];
  const float* bm1 = (const float*)d_in[6];
  const float* Wm2 = (const float*)d_in[7];
  const float* bm2 = (const float*)d_in[8];
  const float* Wdw = (const float*)d_in[9];
  const float* bdw = (const float*)d_in[10];
  const float* Wp  = (const float*)d_in[11];
  const float* bp  = (const float*)d_in[12];

  // per-image fp32 workspace (reused across b):
  //   [0, 75497472)            qkv_b  fp32 [1024][64][288] (t_b aliases)
  //   [75497472, 100663296)    v_b    fp32 [96][65536]
  //   [100663296, 125829120)   o_b    fp32 [96][65536]
  //   [125829120, 125878272)   bias_ws fp32 [3][64][64]
  //   [125878272, 125988864)   WT  fp32 [96][288]
  //   [125988864, 126025728)   WTp fp32 [96][96]
  char* ws = (char*)d_ws;
  float* qkv_b = (float*)ws;
  float* t_b   = (float*)ws;
  float* v_b   = (float*)(ws + 75497472);
  float* o_b   = (float*)(ws + 100663296);
  float* bias_ws = (float*)(ws + 125829120);
  float* WT    = (float*)(ws + 125878272);
  float* WTp   = (float*)(ws + 125988864);

  k0_wt<<<108, 256, 0, stream>>>(Wqk, Wv, Wp, WT, WTp);
  k2_bias<<<16, 256, 0, stream>>>(Wm1, bm1, Wm2, bm2, bias_ws);
  for (int b = 0; b < 4; b++) {
    k1_qkv<<<dim3(1024, 3), 256, 0, stream>>>(x, WT, bqk, bv, qkv_b, v_b, b);
    k3_attn<<<dim3(1024, 3), 64, 0, stream>>>(qkv_b, bias_ws, o_b);
    k4_dw<<<24576, 256, 0, stream>>>(v_b, o_b, Wdw, bdw, t_b);
    k5_proj<<<1024, 256, 0, stream>>>(t_b, WTp, bp, (float*)d_out, b);
  }
}